// Round 5
// baseline (67.916 us; speedup 1.0000x reference)
//
#include <hip/hip_runtime.h>

#define NS    88     // species
#define CCH   128    // channels
#define GY    16     // atom stripes per species in main kernel
#define BCAP  16384  // per-species bucket capacity
#define SCATB 64     // scatter blocks in k_setup

typedef float f32x4 __attribute__((ext_vector_type(4)));

// multiset tables (must match k_main's monomial ordering)
__device__ const int TRI[20][3] = {
    {0,0,0},{0,0,1},{0,0,2},{0,0,3},{0,1,1},{0,1,2},{0,1,3},{0,2,2},{0,2,3},{0,3,3},
    {1,1,1},{1,1,2},{1,1,3},{1,2,2},{1,2,3},{1,3,3},
    {2,2,2},{2,2,3},{2,3,3},
    {3,3,3}};
__device__ const int PAIR[10][2] = {
    {0,0},{0,1},{0,2},{0,3},{1,1},{1,2},{1,3},{2,2},{2,3},{3,3}};

// ---------------- fused setup kernel ----------------
// blocks [0, SCATB): atom-parallel atomic scatter into per-species buckets.
// blocks [SCATB, SCATB+44): coefficient table build.
//   Stage A (cooperative, 536 jobs strided by 256): symmetrize U bases into LDS.
//   Stage B: per (s,c) thread contracts LDS bases with its 16 weight scalars.
// T layout: [s][c][34][4]; m: 0..19 cubic (a<=b<=d), 20..29 pairs, 30..33 linear;
// component: [0]=0e, [1..3]=1o.

__global__ __launch_bounds__(256) void k_setup(
    const int* __restrict__ species, int N,
    const float* __restrict__ u1_0e, const float* __restrict__ w1_0e,
    const float* __restrict__ u1_1o, const float* __restrict__ w1_1o,
    const float* __restrict__ u2_0e, const float* __restrict__ w2_0e,
    const float* __restrict__ u2_1o, const float* __restrict__ w2_1o,
    const float* __restrict__ u3_0e, const float* __restrict__ w3_0e,
    const float* __restrict__ u3_1o, const float* __restrict__ w3_1o,
    float* __restrict__ T, int* __restrict__ cursor, int* __restrict__ list) {

    __shared__ float S3e[20][4];
    __shared__ float S3o[20][6][3];
    __shared__ float S2e[10][2];
    __shared__ float S2o[10][2][3];
    __shared__ float S1e[4];
    __shared__ float S1o[4][3];

    if (blockIdx.x < SCATB) {
        // ---- atom-parallel scatter (bucket order nondeterministic; per-atom
        //      output is order-independent, so d_out is still deterministic) ----
        int stride = SCATB * 256;
        for (int n = blockIdx.x * 256 + threadIdx.x; n < N; n += stride) {
            int s = species[n];
            int p = atomicAdd(&cursor[s], 1);
            list[s * BCAP + p] = n;
        }
        return;
    }

    // ---- stage A: symmetrized bases into LDS (536 jobs, block = 256 threads) ----
    for (int t = threadIdx.x; t < 536; t += 256) {
        if (t < 80) {                       // S3e: m 0..19, k 0..3
            int m = t >> 2, k = t & 3;
            int a = TRI[m][0], b = TRI[m][1], d = TRI[m][2];
            int P[6][3] = {{a,b,d},{a,d,b},{b,a,d},{b,d,a},{d,a,b},{d,b,a}};
            float acc = 0.f;
#pragma unroll
            for (int p = 0; p < 6; ++p)
                acc += u3_0e[((P[p][0] * 4 + P[p][1]) * 4 + P[p][2]) * 4 + k];
            float inv = (a == d) ? (1.f / 6.f) : ((a == b || b == d) ? 0.5f : 1.f);
            S3e[m][k] = acc * inv;
        } else if (t < 440) {               // S3o: m 0..19, k 0..5, i 0..2
            int r = t - 80;
            int m = r / 18, j = r % 18, k = j / 3, i = j % 3;
            int a = TRI[m][0], b = TRI[m][1], d = TRI[m][2];
            int P[6][3] = {{a,b,d},{a,d,b},{b,a,d},{b,d,a},{d,a,b},{d,b,a}};
            float acc = 0.f;
#pragma unroll
            for (int p = 0; p < 6; ++p)
                acc += u3_1o[(((P[p][0] * 4 + P[p][1]) * 4 + P[p][2]) * 6 + k) * 3 + i];
            float inv = (a == d) ? (1.f / 6.f) : ((a == b || b == d) ? 0.5f : 1.f);
            S3o[m][k][i] = acc * inv;
        } else if (t < 460) {               // S2e
            int r = t - 440;
            int m = r >> 1, k = r & 1;
            int a = PAIR[m][0], b = PAIR[m][1];
            float acc = u2_0e[(a * 4 + b) * 2 + k];
            if (a != b) acc += u2_0e[(b * 4 + a) * 2 + k];
            S2e[m][k] = acc;
        } else if (t < 520) {               // S2o
            int r = t - 460;
            int m = r / 6, j = r % 6, k = j / 3, i = j % 3;
            int a = PAIR[m][0], b = PAIR[m][1];
            float acc = u2_1o[((a * 4 + b) * 2 + k) * 3 + i];
            if (a != b) acc += u2_1o[((b * 4 + a) * 2 + k) * 3 + i];
            S2o[m][k][i] = acc;
        } else if (t < 524) {               // S1e
            int d = t - 520;
            S1e[d] = u1_0e[d];
        } else {                            // S1o (t 524..535)
            int r = t - 524;
            S1o[r / 3][r % 3] = u1_1o[r];
        }
    }
    __syncthreads();

    // ---- stage B: per (s,c) contraction with weights ----
    int tg = (blockIdx.x - SCATB) * 256 + threadIdx.x;   // 44*256 = 88*128
    int s = tg >> 7, c = tg & 127;

    float wk3e[4], wk3o[6], wk2e[2], wk2o[2];
#pragma unroll
    for (int k = 0; k < 4; ++k) wk3e[k] = w3_0e[(s * 4 + k) * CCH + c];
#pragma unroll
    for (int k = 0; k < 6; ++k) wk3o[k] = w3_1o[(s * 6 + k) * CCH + c];
#pragma unroll
    for (int k = 0; k < 2; ++k) wk2e[k] = w2_0e[(s * 2 + k) * CCH + c];
#pragma unroll
    for (int k = 0; k < 2; ++k) wk2o[k] = w2_1o[(s * 2 + k) * CCH + c];
    float wk1e = w1_0e[s * CCH + c];
    float wk1o = w1_1o[s * CCH + c];

    f32x4* Tsc = reinterpret_cast<f32x4*>(T + ((size_t)s * CCH + c) * 136);
#pragma unroll
    for (int m = 0; m < 20; ++m) {
        f32x4 row;
        float e = 0.f;
#pragma unroll
        for (int k = 0; k < 4; ++k) e = fmaf(S3e[m][k], wk3e[k], e);
        row.x = e;
#pragma unroll
        for (int i = 0; i < 3; ++i) {
            float o = 0.f;
#pragma unroll
            for (int k = 0; k < 6; ++k) o = fmaf(S3o[m][k][i], wk3o[k], o);
            row[1 + i] = o;
        }
        Tsc[m] = row;
    }
#pragma unroll
    for (int m = 0; m < 10; ++m) {
        f32x4 row;
        row.x = fmaf(S2e[m][0], wk2e[0], S2e[m][1] * wk2e[1]);
#pragma unroll
        for (int i = 0; i < 3; ++i)
            row[1 + i] = fmaf(S2o[m][0][i], wk2o[0], S2o[m][1][i] * wk2o[1]);
        Tsc[20 + m] = row;
    }
#pragma unroll
    for (int d = 0; d < 4; ++d) {
        f32x4 row;
        row.x = S1e[d] * wk1e;
#pragma unroll
        for (int i = 0; i < 3; ++i) row[1 + i] = S1o[d][i] * wk1o;
        Tsc[30 + d] = row;
    }
}

// ---------------- main kernel ----------------
// Block = 128 threads (one channel each), blockIdx.x = species, blockIdx.y = stripe.
// 34 x f32x4 coef rows in VGPRs, reused across the stripe's atoms; next atom's x
// prefetched during compute. NT x-loads / out-stores keep the 6.1 MB table L2-resident.

__global__ __launch_bounds__(128, 2) void k_main(
    const float* __restrict__ x, const float* __restrict__ T,
    const int* __restrict__ list, const int* __restrict__ counts,
    float* __restrict__ out) {
    int s = blockIdx.x;
    int c = threadIdx.x;
    int cnt = counts[s];
    int t = (int)blockIdx.y;
    if (t >= cnt) return;
    const int* bucket = list + s * BCAP;

    const f32x4* Tsc = reinterpret_cast<const f32x4*>(T + ((size_t)s * CCH + c) * 136);
    f32x4 coef[34];
#pragma unroll
    for (int m = 0; m < 34; ++m) coef[m] = Tsc[m];

    int n = bucket[t];
    f32x4 xv = __builtin_nontemporal_load(
        reinterpret_cast<const f32x4*>(x + (size_t)n * 512 + (c << 2)));

    while (true) {
        int tn = t + GY;
        bool more = tn < cnt;
        int nn = 0;
        f32x4 xn = (f32x4)(0.f);
        if (more) {
            nn = bucket[tn];
            xn = __builtin_nontemporal_load(
                reinterpret_cast<const f32x4*>(x + (size_t)nn * 512 + (c << 2)));
        }

        float xa[4] = {xv.x, xv.y, xv.z, xv.w};
        float mono[34];
        int q = 0;
#pragma unroll
        for (int a = 0; a < 4; ++a)
#pragma unroll
        for (int b = a; b < 4; ++b) { mono[20 + q] = xa[a] * xa[b]; ++q; }
        int m3 = 0;
#pragma unroll
        for (int a = 0; a < 4; ++a)
#pragma unroll
        for (int b = a; b < 4; ++b)
#pragma unroll
        for (int d = b; d < 4; ++d) { mono[m3] = mono[20 + (a * (7 - a)) / 2 + b] * xa[d]; ++m3; }
#pragma unroll
        for (int d = 0; d < 4; ++d) mono[30 + d] = xa[d];

        float o0 = 0.f, o1 = 0.f, o2 = 0.f, o3 = 0.f;
#pragma unroll
        for (int m = 0; m < 34; ++m) {
            float mv = mono[m];
            o0 = fmaf(coef[m].x, mv, o0);
            o1 = fmaf(coef[m].y, mv, o1);
            o2 = fmaf(coef[m].z, mv, o2);
            o3 = fmaf(coef[m].w, mv, o3);
        }
        float* orow = out + (size_t)n * 512;
        __builtin_nontemporal_store(o0, orow + c);
        __builtin_nontemporal_store(o1, orow + CCH + 3 * c + 0);
        __builtin_nontemporal_store(o2, orow + CCH + 3 * c + 1);
        __builtin_nontemporal_store(o3, orow + CCH + 3 * c + 2);

        if (!more) break;
        t = tn; n = nn; xv = xn;
    }
}

// ---------------- launch ----------------

extern "C" void kernel_launch(void* const* d_in, const int* in_sizes, int n_in,
                              void* d_out, int out_size, void* d_ws, size_t ws_size,
                              hipStream_t stream) {
    const float* x     = (const float*)d_in[0];
    const float* u1_0e = (const float*)d_in[1];
    const float* w1_0e = (const float*)d_in[2];
    const float* u1_1o = (const float*)d_in[3];
    const float* w1_1o = (const float*)d_in[4];
    const float* u2_0e = (const float*)d_in[5];
    const float* w2_0e = (const float*)d_in[6];
    const float* u2_1o = (const float*)d_in[7];
    const float* w2_1o = (const float*)d_in[8];
    const float* u3_0e = (const float*)d_in[9];
    const float* w3_0e = (const float*)d_in[10];
    const float* u3_1o = (const float*)d_in[11];
    const float* w3_1o = (const float*)d_in[12];
    const int*   spec  = (const int*)d_in[13];
    int N = in_sizes[13];
    float* out = (float*)d_out;

    char* ws = (char*)d_ws;
    float* T    = (float*)ws;                                // NS*CCH*136 floats
    size_t tbytes = (size_t)NS * CCH * 136 * sizeof(float);
    int* list   = (int*)(ws + tbytes);                       // NS*BCAP ints
    int* cursor = list + (size_t)NS * BCAP;                  // NS ints

    hipMemsetAsync(cursor, 0, NS * sizeof(int), stream);
    int table_blocks = (NS * CCH) / 256;                     // 44
    k_setup<<<SCATB + table_blocks, 256, 0, stream>>>(
        spec, N,
        u1_0e, w1_0e, u1_1o, w1_1o,
        u2_0e, w2_0e, u2_1o, w2_1o,
        u3_0e, w3_0e, u3_1o, w3_1o,
        T, cursor, list);
    k_main<<<dim3(NS, GY), 128, 0, stream>>>(x, T, list, cursor, out);
}

// Round 6
// 50.601 us; speedup vs baseline: 1.3422x; 1.3422x over previous
//
#include <hip/hip_runtime.h>

#define NS    88     // species
#define CCH   128    // channels
#define GY    16     // atom stripes per species in main kernel
#define BCAP  16384  // per-species bucket capacity
#define HB    64     // histogram/scatter blocks (64*256 = 16384 atoms)

typedef float f32x4 __attribute__((ext_vector_type(4)));

// multiset tables (must match k_main's monomial ordering)
__device__ const int TRI[20][3] = {
    {0,0,0},{0,0,1},{0,0,2},{0,0,3},{0,1,1},{0,1,2},{0,1,3},{0,2,2},{0,2,3},{0,3,3},
    {1,1,1},{1,1,2},{1,1,3},{1,2,2},{1,2,3},{1,3,3},
    {2,2,2},{2,2,3},{2,3,3},
    {3,3,3}};
__device__ const int PAIR[10][2] = {
    {0,0},{0,1},{0,2},{0,3},{1,1},{1,2},{1,3},{2,2},{2,3},{3,3}};

// ---------------- kernel 1: per-block histogram + coefficient table ----------------
// blocks [0, HB): LDS histogram of a 256-atom chunk -> blockhist[b][s].
// blocks [HB, HB+44): coefficient table build (stage A: symmetrize U into LDS;
//   stage B: per (s,c) contraction with weights). T layout [s][c][34][4];
//   m: 0..19 cubic (a<=b<=d), 20..29 pairs, 30..33 linear; comp [0]=0e, [1..3]=1o.

__global__ __launch_bounds__(256) void k_sort1(
    const int* __restrict__ species, int N,
    const float* __restrict__ u1_0e, const float* __restrict__ w1_0e,
    const float* __restrict__ u1_1o, const float* __restrict__ w1_1o,
    const float* __restrict__ u2_0e, const float* __restrict__ w2_0e,
    const float* __restrict__ u2_1o, const float* __restrict__ w2_1o,
    const float* __restrict__ u3_0e, const float* __restrict__ w3_0e,
    const float* __restrict__ u3_1o, const float* __restrict__ w3_1o,
    float* __restrict__ T, int* __restrict__ blockhist) {

    __shared__ float S3e[20][4];
    __shared__ float S3o[20][6][3];
    __shared__ float S2e[10][2];
    __shared__ float S2o[10][2][3];
    __shared__ float S1e[4];
    __shared__ float S1o[4][3];
    __shared__ int hist[NS];

    int tid = threadIdx.x;

    if (blockIdx.x < HB) {
        for (int i = tid; i < NS; i += 256) hist[i] = 0;
        __syncthreads();
        int n = blockIdx.x * 256 + tid;
        if (n < N) atomicAdd(&hist[species[n]], 1);
        __syncthreads();
        for (int s = tid; s < NS; s += 256) blockhist[blockIdx.x * NS + s] = hist[s];
        return;
    }

    // ---- stage A: symmetrized bases into LDS (536 jobs, 256 threads) ----
    for (int t = tid; t < 536; t += 256) {
        if (t < 80) {
            int m = t >> 2, k = t & 3;
            int a = TRI[m][0], b = TRI[m][1], d = TRI[m][2];
            int P[6][3] = {{a,b,d},{a,d,b},{b,a,d},{b,d,a},{d,a,b},{d,b,a}};
            float acc = 0.f;
#pragma unroll
            for (int p = 0; p < 6; ++p)
                acc += u3_0e[((P[p][0] * 4 + P[p][1]) * 4 + P[p][2]) * 4 + k];
            float inv = (a == d) ? (1.f / 6.f) : ((a == b || b == d) ? 0.5f : 1.f);
            S3e[m][k] = acc * inv;
        } else if (t < 440) {
            int r = t - 80;
            int m = r / 18, j = r % 18, k = j / 3, i = j % 3;
            int a = TRI[m][0], b = TRI[m][1], d = TRI[m][2];
            int P[6][3] = {{a,b,d},{a,d,b},{b,a,d},{b,d,a},{d,a,b},{d,b,a}};
            float acc = 0.f;
#pragma unroll
            for (int p = 0; p < 6; ++p)
                acc += u3_1o[(((P[p][0] * 4 + P[p][1]) * 4 + P[p][2]) * 6 + k) * 3 + i];
            float inv = (a == d) ? (1.f / 6.f) : ((a == b || b == d) ? 0.5f : 1.f);
            S3o[m][k][i] = acc * inv;
        } else if (t < 460) {
            int r = t - 440;
            int m = r >> 1, k = r & 1;
            int a = PAIR[m][0], b = PAIR[m][1];
            float acc = u2_0e[(a * 4 + b) * 2 + k];
            if (a != b) acc += u2_0e[(b * 4 + a) * 2 + k];
            S2e[m][k] = acc;
        } else if (t < 520) {
            int r = t - 460;
            int m = r / 6, j = r % 6, k = j / 3, i = j % 3;
            int a = PAIR[m][0], b = PAIR[m][1];
            float acc = u2_1o[((a * 4 + b) * 2 + k) * 3 + i];
            if (a != b) acc += u2_1o[((b * 4 + a) * 2 + k) * 3 + i];
            S2o[m][k][i] = acc;
        } else if (t < 524) {
            int d = t - 520;
            S1e[d] = u1_0e[d];
        } else {
            int r = t - 524;
            S1o[r / 3][r % 3] = u1_1o[r];
        }
    }
    __syncthreads();

    // ---- stage B: per (s,c) contraction with weights ----
    int tg = (blockIdx.x - HB) * 256 + tid;              // 44*256 = 88*128
    int s = tg >> 7, c = tg & 127;

    float wk3e[4], wk3o[6], wk2e[2], wk2o[2];
#pragma unroll
    for (int k = 0; k < 4; ++k) wk3e[k] = w3_0e[(s * 4 + k) * CCH + c];
#pragma unroll
    for (int k = 0; k < 6; ++k) wk3o[k] = w3_1o[(s * 6 + k) * CCH + c];
#pragma unroll
    for (int k = 0; k < 2; ++k) wk2e[k] = w2_0e[(s * 2 + k) * CCH + c];
#pragma unroll
    for (int k = 0; k < 2; ++k) wk2o[k] = w2_1o[(s * 2 + k) * CCH + c];
    float wk1e = w1_0e[s * CCH + c];
    float wk1o = w1_1o[s * CCH + c];

    f32x4* Tsc = reinterpret_cast<f32x4*>(T + ((size_t)s * CCH + c) * 136);
#pragma unroll
    for (int m = 0; m < 20; ++m) {
        f32x4 row;
        float e = 0.f;
#pragma unroll
        for (int k = 0; k < 4; ++k) e = fmaf(S3e[m][k], wk3e[k], e);
        row.x = e;
#pragma unroll
        for (int i = 0; i < 3; ++i) {
            float o = 0.f;
#pragma unroll
            for (int k = 0; k < 6; ++k) o = fmaf(S3o[m][k][i], wk3o[k], o);
            row[1 + i] = o;
        }
        Tsc[m] = row;
    }
#pragma unroll
    for (int m = 0; m < 10; ++m) {
        f32x4 row;
        row.x = fmaf(S2e[m][0], wk2e[0], S2e[m][1] * wk2e[1]);
#pragma unroll
        for (int i = 0; i < 3; ++i)
            row[1 + i] = fmaf(S2o[m][0][i], wk2o[0], S2o[m][1][i] * wk2o[1]);
        Tsc[20 + m] = row;
    }
#pragma unroll
    for (int d = 0; d < 4; ++d) {
        f32x4 row;
        row.x = S1e[d] * wk1e;
#pragma unroll
        for (int i = 0; i < 3; ++i) row[1 + i] = S1o[d][i] * wk1o;
        Tsc[30 + d] = row;
    }
}

// ---------------- kernel 2: per-species exclusive scan over block counts ----------------
// 22 blocks x 256 = 88 waves; wave g handles species g: lane l holds blockhist[l][g].

__global__ __launch_bounds__(256) void k_off(
    const int* __restrict__ blockhist, int* __restrict__ boff, int* __restrict__ counts) {
    int tid = threadIdx.x, lane = tid & 63, w = tid >> 6;
    int g = blockIdx.x * 4 + w;                  // species, 0..87
    int v = blockhist[lane * NS + g];
    int x = v;
#pragma unroll
    for (int o = 1; o < 64; o <<= 1) {
        int y = __shfl_up(x, o, 64);
        if (lane >= o) x += y;
    }
    int excl = x - v;
    boff[lane * NS + g] = excl;
    if (lane == 63) counts[g] = excl + v;
}

// ---------------- kernel 3: deterministic ranked scatter ----------------
// Rank of atom n within its block = #earlier threads in block with same species,
// via 7-bit ballot equivalence classes (intra-wave) + per-wave LDS histograms.

__global__ __launch_bounds__(256) void k_scat(
    const int* __restrict__ species, int N,
    const int* __restrict__ boff, int* __restrict__ list) {
    __shared__ int wh[4][NS];
    int tid = threadIdx.x, lane = tid & 63, w = tid >> 6;
    for (int i = tid; i < 4 * NS; i += 256) ((int*)wh)[i] = 0;
    int n = blockIdx.x * 256 + tid;
    int s = (n < N) ? species[n] : -1;
    __syncthreads();
    if (s >= 0) atomicAdd(&wh[w][s], 1);

    // intra-wave rank via bitwise ballots (all 64 lanes participate)
    unsigned v = (s >= 0) ? (unsigned)s : 127u;  // 127 unused by valid species (<88)
    unsigned long long eq = ~0ull;
#pragma unroll
    for (int bit = 0; bit < 7; ++bit) {
        unsigned long long b = __ballot((v >> bit) & 1);
        eq &= ((v >> bit) & 1) ? b : ~b;
    }
    int rank = __popcll(eq & ((1ull << lane) - 1));
    __syncthreads();
    if (s >= 0) {
#pragma unroll
        for (int w2 = 0; w2 < 3; ++w2) if (w2 < w) rank += wh[w2][s];
        int pos = boff[blockIdx.x * NS + s] + rank;
        list[s * BCAP + pos] = n;
    }
}

// ---------------- main kernel ----------------
// Block = 128 threads (one channel each), blockIdx.x = species, blockIdx.y = stripe.
// 34 x f32x4 coef rows in VGPRs, reused across the stripe's atoms; next atom's x
// prefetched during compute. NT x-loads / out-stores keep the 6.1 MB table cache-resident.

__global__ __launch_bounds__(128, 2) void k_main(
    const float* __restrict__ x, const float* __restrict__ T,
    const int* __restrict__ list, const int* __restrict__ counts,
    float* __restrict__ out) {
    int s = blockIdx.x;
    int c = threadIdx.x;
    int cnt = counts[s];
    int t = (int)blockIdx.y;
    if (t >= cnt) return;
    const int* bucket = list + s * BCAP;

    const f32x4* Tsc = reinterpret_cast<const f32x4*>(T + ((size_t)s * CCH + c) * 136);
    f32x4 coef[34];
#pragma unroll
    for (int m = 0; m < 34; ++m) coef[m] = Tsc[m];

    int n = bucket[t];
    f32x4 xv = __builtin_nontemporal_load(
        reinterpret_cast<const f32x4*>(x + (size_t)n * 512 + (c << 2)));

    while (true) {
        int tn = t + GY;
        bool more = tn < cnt;
        int nn = 0;
        f32x4 xn = (f32x4)(0.f);
        if (more) {
            nn = bucket[tn];
            xn = __builtin_nontemporal_load(
                reinterpret_cast<const f32x4*>(x + (size_t)nn * 512 + (c << 2)));
        }

        float xa[4] = {xv.x, xv.y, xv.z, xv.w};
        float mono[34];
        int q = 0;
#pragma unroll
        for (int a = 0; a < 4; ++a)
#pragma unroll
        for (int b = a; b < 4; ++b) { mono[20 + q] = xa[a] * xa[b]; ++q; }
        int m3 = 0;
#pragma unroll
        for (int a = 0; a < 4; ++a)
#pragma unroll
        for (int b = a; b < 4; ++b)
#pragma unroll
        for (int d = b; d < 4; ++d) { mono[m3] = mono[20 + (a * (7 - a)) / 2 + b] * xa[d]; ++m3; }
#pragma unroll
        for (int d = 0; d < 4; ++d) mono[30 + d] = xa[d];

        float o0 = 0.f, o1 = 0.f, o2 = 0.f, o3 = 0.f;
#pragma unroll
        for (int m = 0; m < 34; ++m) {
            float mv = mono[m];
            o0 = fmaf(coef[m].x, mv, o0);
            o1 = fmaf(coef[m].y, mv, o1);
            o2 = fmaf(coef[m].z, mv, o2);
            o3 = fmaf(coef[m].w, mv, o3);
        }
        float* orow = out + (size_t)n * 512;
        __builtin_nontemporal_store(o0, orow + c);
        __builtin_nontemporal_store(o1, orow + CCH + 3 * c + 0);
        __builtin_nontemporal_store(o2, orow + CCH + 3 * c + 1);
        __builtin_nontemporal_store(o3, orow + CCH + 3 * c + 2);

        if (!more) break;
        t = tn; n = nn; xv = xn;
    }
}

// ---------------- launch ----------------

extern "C" void kernel_launch(void* const* d_in, const int* in_sizes, int n_in,
                              void* d_out, int out_size, void* d_ws, size_t ws_size,
                              hipStream_t stream) {
    const float* x     = (const float*)d_in[0];
    const float* u1_0e = (const float*)d_in[1];
    const float* w1_0e = (const float*)d_in[2];
    const float* u1_1o = (const float*)d_in[3];
    const float* w1_1o = (const float*)d_in[4];
    const float* u2_0e = (const float*)d_in[5];
    const float* w2_0e = (const float*)d_in[6];
    const float* u2_1o = (const float*)d_in[7];
    const float* w2_1o = (const float*)d_in[8];
    const float* u3_0e = (const float*)d_in[9];
    const float* w3_0e = (const float*)d_in[10];
    const float* u3_1o = (const float*)d_in[11];
    const float* w3_1o = (const float*)d_in[12];
    const int*   spec  = (const int*)d_in[13];
    int N = in_sizes[13];
    float* out = (float*)d_out;

    char* ws = (char*)d_ws;
    float* T       = (float*)ws;                             // NS*CCH*136 floats
    size_t tbytes  = (size_t)NS * CCH * 136 * sizeof(float);
    int* list      = (int*)(ws + tbytes);                    // NS*BCAP ints
    int* counts    = list + (size_t)NS * BCAP;               // NS ints
    int* blockhist = counts + NS;                            // HB*NS ints
    int* boff      = blockhist + HB * NS;                    // HB*NS ints

    int table_blocks = (NS * CCH) / 256;                     // 44
    k_sort1<<<HB + table_blocks, 256, 0, stream>>>(
        spec, N,
        u1_0e, w1_0e, u1_1o, w1_1o,
        u2_0e, w2_0e, u2_1o, w2_1o,
        u3_0e, w3_0e, u3_1o, w3_1o,
        T, blockhist);
    k_off<<<NS / 4, 256, 0, stream>>>(blockhist, boff, counts);
    k_scat<<<HB, 256, 0, stream>>>(spec, N, boff, list);
    k_main<<<dim3(NS, GY), 128, 0, stream>>>(x, T, list, counts, out);
}